// Round 3
// baseline (130.965 us; speedup 1.0000x reference)
//
#include <hip/hip_runtime.h>

#define B_   32
#define ICN  1152
#define OCN  10
#define IDN  8
#define ODN  16
#define ODH  8                  // od half width (split across 2 lanes)
#define NIT  5
#define EPS  1e-20f
#define OUTN (B_ * OCN * ODN)   // 5120
#define BGRP 11                 // ceil(32 b / 3 groups per wave)
#define NWAVE (BGRP * ICN)      // 12672 logical waves
#define WPB  8                  // waves per block (512 threads, 8 consecutive ic)
#define NBLK (NWAVE / WPB)      // 1584 workgroups

// Pair-swap lanes (2k,2k+1) via DPP quad_perm [1,0,3,2] = 0xB1.
// Pure VALU (~2 cyc); keeps the od-pair reduction off the LDS pipe.
__device__ __forceinline__ float dpp_swap1(float x) {
  return __int_as_float(__builtin_amdgcn_update_dpp(
      0, __float_as_int(x), 0xB1, 0xF, 0xF, true));
}

// ---------------------------------------------------------------------------
// R2 experiment: NO WORKSPACE. Per-wave compute is bit-identical to R1
// (DPP pair reductions, phase-batched NNMF); only the output path changes.
// 8 waves/block cover 8 consecutive ic within ONE bgrp (1152 % 8 == 0), so
// all waves in a block contribute to the SAME (b,oc,od) outputs -> reduce
// 8x in LDS, then one atomicAdd per valid (lane,k) slot. 737K atomics total,
// 144 contenders/address. Removes caps_reduce and ~47 MB of ws HBM traffic,
// and decouples the measurement from harness ws re-poison (43.5 us fills).
//
// LDS layout red[w][k][l] (w=wave, k=od-elem, l=lane): writes are 8x
// ds_write_b32 with consecutive lanes -> conflict-free; read phase assigns
// thread s -> (k = s>>6, l = s&63), summing over w at stride 512 floats ->
// consecutive threads read consecutive addresses -> conflict-free.
// ---------------------------------------------------------------------------
__global__ __launch_bounds__(512, 4) void caps_main(
    const float* __restrict__ xg, const float* __restrict__ wg,
    float* __restrict__ outg) {
  __shared__ float red[WPB * 512];   // 16 KB
  const int l = threadIdx.x & 63;
  const int w = threadIdx.x >> 6;
  const int wid = blockIdx.x * WPB + w;  // global wave id
  const int ic = wid % ICN;
  const int bgrp = wid / ICN;    // 0..10, uniform across the block
  const int grp = l / 20;        // 0..3 (3 = idle lanes 60..63)
  const int q = l % 20;
  const int oc = q >> 1;         // 0..9
  const int half = q & 1;        // 0,1
  const int b = bgrp * 3 + grp;
  const int bb = (b < B_) ? b : (B_ - 1);   // clamp for loads only

  // ---- weights slice -> registers: w[ic][oc][id][half*8 .. +8) ----
  float wr[IDN][ODH];
  {
    const float* wp = wg + ((size_t)ic * OCN + oc) * (IDN * ODN) + half * ODH;
#pragma unroll
    for (int id = 0; id < IDN; ++id) {
      const float4 v0 = *(const float4*)(wp + id * ODN);
      const float4 v1 = *(const float4*)(wp + id * ODN + 4);
      wr[id][0] = v0.x; wr[id][1] = v0.y; wr[id][2] = v0.z; wr[id][3] = v0.w;
      wr[id][4] = v1.x; wr[id][5] = v1.y; wr[id][6] = v1.z; wr[id][7] = v1.w;
    }
  }

  // ---- x[b,ic,:] normalized over id ----
  float xn[IDN];
  {
    const float* xp = xg + ((size_t)bb * ICN + ic) * IDN;
    const float4 a0 = ((const float4*)xp)[0];
    const float4 a1 = ((const float4*)xp)[1];
    xn[0] = a0.x; xn[1] = a0.y; xn[2] = a0.z; xn[3] = a0.w;
    xn[4] = a1.x; xn[5] = a1.y; xn[6] = a1.z; xn[7] = a1.w;
    const float s = ((xn[0] + xn[1]) + (xn[2] + xn[3])) +
                    ((xn[4] + xn[5]) + (xn[6] + xn[7]));
    const float r = __builtin_amdgcn_rcpf(s + EPS);
#pragma unroll
    for (int i = 0; i < IDN; ++i) xn[i] *= r;
  }

  // ---- NNMF iterations (phase-batched for ILP, DPP for pair reductions) ----
  float h[ODH];
#pragma unroll
  for (int k = 0; k < ODH; ++k) h[k] = 1.0f / ODN;

  for (int it = 0; it < NIT; ++it) {
    float pd[IDN];
#pragma unroll
    for (int id = 0; id < IDN; ++id) {
      float p = 0.f;
#pragma unroll
      for (int k = 0; k < ODH; ++k) p = fmaf(h[k], wr[id][k], p);
      pd[id] = p;
    }
    float tc[IDN];
#pragma unroll
    for (int id = 0; id < IDN; ++id) {
      const float den = pd[id] + dpp_swap1(pd[id]);   // full 16-od sum
      tc[id] = xn[id] * __builtin_amdgcn_rcpf(den + EPS);
    }
    float hacc[ODH];
#pragma unroll
    for (int k = 0; k < ODH; ++k) hacc[k] = wr[0][k] * tc[0];
#pragma unroll
    for (int id = 1; id < IDN; ++id)
#pragma unroll
      for (int k = 0; k < ODH; ++k) hacc[k] = fmaf(wr[id][k], tc[id], hacc[k]);
#pragma unroll
    for (int k = 0; k < ODH; ++k) h[k] *= hacc[k];
    const float ps = ((h[0] + h[1]) + (h[2] + h[3])) +
                     ((h[4] + h[5]) + (h[6] + h[7]));
    const float hs = ps + dpp_swap1(ps);              // full 16-od sum
    const float r = __builtin_amdgcn_rcpf(hs + EPS);
#pragma unroll
    for (int k = 0; k < ODH; ++k) h[k] *= r;
  }

  // ---- alpha = sum_id (sum_od h*w) * xn, normalized over oc ----
  float ap = 0.f;
#pragma unroll
  for (int id = 0; id < IDN; ++id) {
    float rec = 0.f;
#pragma unroll
    for (int k = 0; k < ODH; ++k) rec = fmaf(h[k], wr[id][k], rec);
    ap = fmaf(rec, xn[id], ap);
  }
  const float af = ap + dpp_swap1(ap);                // full alpha(b,ic,oc)
  float asum = 0.f;
  const int gbase = grp * 20;
#pragma unroll
  for (int k = 0; k < OCN; ++k) asum += __shfl(af, gbase + 2 * k, 64);
  const float an = af * __builtin_amdgcn_rcpf(asum + EPS);

  // ---- block-level reduction over the 8 ic, then one atomic per slot ----
  // write red[w][k][l]; invalid lanes write garbage-but-finite, never read
  // for the atomic (read side recomputes validity from its own lane).
#pragma unroll
  for (int k = 0; k < ODH; ++k)
    red[w * 512 + k * 64 + l] = h[k] * an;

  __syncthreads();

  {
    const int k2 = threadIdx.x >> 6;   // 0..7
    const int l2 = threadIdx.x & 63;
    const int grp2 = l2 / 20;
    const int q2 = l2 % 20;
    const int oc2 = q2 >> 1;
    const int half2 = q2 & 1;
    const int b2 = bgrp * 3 + grp2;
    float s = 0.f;
#pragma unroll
    for (int ww = 0; ww < WPB; ++ww)
      s += red[ww * 512 + k2 * 64 + l2];
    if (grp2 < 3 && b2 < B_)
      atomicAdd(outg + (b2 * OCN + oc2) * ODN + half2 * ODH + k2, s);
  }
}

extern "C" void kernel_launch(void* const* d_in, const int* in_sizes, int n_in,
                              void* d_out, int out_size, void* d_ws, size_t ws_size,
                              hipStream_t stream) {
  const float* x = (const float*)d_in[0];
  const float* w = (const float*)d_in[1];
  float* out = (float*)d_out;
  (void)d_ws; (void)ws_size;

  hipMemsetAsync(out, 0, OUTN * sizeof(float), stream);
  caps_main<<<NBLK, 512, 0, stream>>>(x, w, out);
}